// Round 4
// baseline (42938.531 us; speedup 1.0000x reference)
//
#include <hip/hip_runtime.h>
#include <hip/hip_bf16.h>
#include <math.h>

#define D 512
#define H 512
#define G3 1536
#define GRU_WGS 32
#define GRU_SLICE 16   // H / GRU_WGS
#define GRU_THREADS 512

__device__ __forceinline__ float sigmoidf_(float x) {
    return __fdividef(1.0f, 1.0f + __expf(-x));
}
__device__ __forceinline__ float tanhf_(float x) {
    // 1 - 2/(1+e^{2x}) ; exact at +-inf, ~2ulp mid-range
    return 1.0f - 2.0f * __fdividef(1.0f, 1.0f + __expf(2.0f * x));
}

// ---------------- degree / norm ----------------
__global__ void deg_init(float* deg, int N) {
    int i = blockIdx.x * blockDim.x + threadIdx.x;
    if (i < N) deg[i] = 2.0f;   // two self loops per node
}
__global__ void deg_count(const int* __restrict__ ei, float* deg, int E) {
    int e = blockIdx.x * blockDim.x + threadIdx.x;
    if (e < E) atomicAdd(&deg[ei[E + e]], 1.0f);
}
__global__ void deg_inv(const float* __restrict__ deg, float* dinv, int N) {
    int i = blockIdx.x * blockDim.x + threadIdx.x;
    if (i < N) dinv[i] = rsqrtf(deg[i]);
}

// ---------------- f32 tiled GEMM ----------------
template<bool NT, bool BIAS>
__global__ __launch_bounds__(256) void gemm64(
    const float* __restrict__ A, const float* __restrict__ B,
    const float* __restrict__ bias, float* __restrict__ C,
    int M, int N, int K)
{
    __shared__ float As[16][68];
    __shared__ float Bs[16][68];
    const int tid = threadIdx.x;
    const int tx = tid & 15, ty = tid >> 4;
    const int bm = blockIdx.y * 64, bn = blockIdx.x * 64;
    float acc[4][4] = {};
    for (int k0 = 0; k0 < K; k0 += 16) {
        #pragma unroll
        for (int l = 0; l < 4; ++l) {
            int idx = tid + l * 256;
            int m = idx >> 4, kk = idx & 15;
            As[kk][m] = A[(size_t)(bm + m) * K + (k0 + kk)];
            if (NT) {
                int n = idx >> 4, k2 = idx & 15;
                Bs[k2][n] = B[(size_t)(bn + n) * K + (k0 + k2)];
            } else {
                int k2 = idx >> 6, n = idx & 63;
                Bs[k2][n] = B[(size_t)(k0 + k2) * N + (bn + n)];
            }
        }
        __syncthreads();
        #pragma unroll
        for (int kk = 0; kk < 16; ++kk) {
            float4 av = *(const float4*)&As[kk][ty * 4];
            float4 bv = *(const float4*)&Bs[kk][tx * 4];
            float a[4] = {av.x, av.y, av.z, av.w};
            float b[4] = {bv.x, bv.y, bv.z, bv.w};
            #pragma unroll
            for (int i = 0; i < 4; ++i)
                #pragma unroll
                for (int j = 0; j < 4; ++j)
                    acc[i][j] = fmaf(a[i], b[j], acc[i][j]);
        }
        __syncthreads();
    }
    #pragma unroll
    for (int i = 0; i < 4; ++i)
        #pragma unroll
        for (int j = 0; j < 4; ++j) {
            float v = acc[i][j];
            if (BIAS) v += bias[bn + tx * 4 + j];
            C[(size_t)(bm + ty * 4 + i) * N + (bn + tx * 4 + j)] = v;
        }
}

// ---------------- GCN aggregation ----------------
__global__ void gcn_init(const float* __restrict__ xw, const float* __restrict__ dinv,
                         const float* __restrict__ bias, float* __restrict__ gcn, int N) {
    int n = blockIdx.x;
    int k = threadIdx.x;
    float di = dinv[n];
    gcn[(size_t)n * D + k] = bias[k] + 2.0f * di * di * xw[(size_t)n * D + k];
}
__global__ void scatter_edges(const int* __restrict__ ei, const float* __restrict__ xw,
                              const float* __restrict__ dinv, float* __restrict__ gcn, int E) {
    int e = blockIdx.x;
    int row = ei[e], col = ei[E + e];
    float norm = dinv[row] * dinv[col];
    int k = threadIdx.x;
    atomicAdd(&gcn[(size_t)col * D + k], norm * xw[(size_t)row * D + k]);
}

// ---------------- GRU ----------------
// h exchange: hx[2][512] u64 packing (step_tag<<32 | f32 bits). Value+tag
// travel atomically in one relaxed agent-scope word -> no fences needed.
// elect[0..7]: per-XCD arrival counters ; elect[8]: winner xcd (-1 = none)
__global__ void gru_init(const float* __restrict__ hidden, unsigned long long* hx,
                         int* elect) {
    int i = threadIdx.x;           // 512 threads
    hx[i] = (unsigned long long)__float_as_uint(hidden[i]) & 0xffffffffull;  // tag 0
    hx[H + i] = 0xffffffff00000000ull;
    if (i < 9) elect[i] = (i == 8) ? -1 : 0;
}

// 256 WGs launched (1 per CU). Election keeps the 32 WGs that share one XCD
// (via HW_REG_XCC_ID=20); the rest exit. Correctness does not depend on the
// placement guess: any 32 ranked WGs run the same tagged-word protocol.
__global__ __launch_bounds__(GRU_THREADS, 1) void gru_kernel(
    const float* __restrict__ gi, const float* __restrict__ w_hh,
    const float* __restrict__ b_hh, unsigned long long* hx,
    int* elect, float* __restrict__ out, int T)
{
    const int tid = threadIdx.x;
    const int wave = tid >> 6;
    const int lane = tid & 63;

    __shared__ float h_lds[H];
    __shared__ float dots[48];
    __shared__ int s_rank;

    // ---- same-XCD election ----
    if (tid == 0) {
        int x = __builtin_amdgcn_s_getreg(20 | (7 << 11)) & 7;  // HW_REG_XCC_ID
        int r = __hip_atomic_fetch_add(&elect[x], 1, __ATOMIC_RELAXED,
                                       __HIP_MEMORY_SCOPE_AGENT);
        if (r == GRU_WGS - 1) {
            int exp_ = -1;
            __hip_atomic_compare_exchange_strong(&elect[8], &exp_, x,
                __ATOMIC_RELAXED, __ATOMIC_RELAXED, __HIP_MEMORY_SCOPE_AGENT);
        }
        int win;
        do {
            win = __hip_atomic_load(&elect[8], __ATOMIC_RELAXED,
                                    __HIP_MEMORY_SCOPE_AGENT);
            if (win < 0) __builtin_amdgcn_s_sleep(2);
        } while (win < 0);
        s_rank = (win == x && r < GRU_WGS) ? r : -1;
    }
    __syncthreads();
    const int wg = s_rank;
    if (wg < 0) return;

    // local rows lr = wave*6 + r ; lr<16 -> r-gate, <32 -> z-gate, else n-gate
    float w_reg[6][8];
    float bhh[6];
    #pragma unroll
    for (int r = 0; r < 6; ++r) {
        int lr = wave * 6 + r;
        int grow;
        if (lr < 16)      grow = wg * GRU_SLICE + lr;
        else if (lr < 32) grow = H + wg * GRU_SLICE + (lr - 16);
        else              grow = 2 * H + wg * GRU_SLICE + (lr - 32);
        bhh[r] = b_hh[grow];
        #pragma unroll
        for (int m = 0; m < 8; ++m)
            w_reg[r][m] = w_hh[(size_t)grow * H + lane + 64 * m];
    }

    // gi for t=0 (threads 0..15 hold the 3 gate inputs for their element)
    float gir = 0.f, giz = 0.f, gin = 0.f;
    if (tid < GRU_SLICE) {
        size_t base = (size_t)wg * GRU_SLICE + tid;
        gir = gi[base]; giz = gi[base + H]; gin = gi[base + 2 * H];
    }

    for (int t = 0; t < T; ++t) {
        // ---- consume h_t: poll my tagged word ----
        {
            unsigned long long* p = &hx[(t & 1) * H + tid];
            unsigned long long v = __hip_atomic_load(p, __ATOMIC_RELAXED,
                                                     __HIP_MEMORY_SCOPE_AGENT);
            while ((unsigned int)(v >> 32) != (unsigned int)t) {
                __builtin_amdgcn_s_sleep(1);
                v = __hip_atomic_load(p, __ATOMIC_RELAXED,
                                      __HIP_MEMORY_SCOPE_AGENT);
            }
            h_lds[tid] = __uint_as_float((unsigned int)v);
        }
        __syncthreads();

        // prefetch next step's gi (latency hidden under compute)
        float ngir = 0.f, ngiz = 0.f, ngin = 0.f;
        if (tid < GRU_SLICE && t + 1 < T) {
            size_t base = (size_t)(t + 1) * G3 + (size_t)wg * GRU_SLICE + tid;
            ngir = gi[base]; ngiz = gi[base + H]; ngin = gi[base + 2 * H];
        }

        float hr[8];
        #pragma unroll
        for (int m = 0; m < 8; ++m) hr[m] = h_lds[lane + 64 * m];

        #pragma unroll
        for (int r = 0; r < 6; ++r) {
            float s = 0.f;
            #pragma unroll
            for (int m = 0; m < 8; ++m) s = fmaf(w_reg[r][m], hr[m], s);
            #pragma unroll
            for (int off = 32; off > 0; off >>= 1)
                s += __shfl_xor(s, off, 64);
            if (lane == 0) dots[wave * 6 + r] = s + bhh[r];
        }
        __syncthreads();

        // ---- gates on threads < 16 ; publish tagged h_{t+1} first ----
        if (tid < GRU_SLICE) {
            int j = wg * GRU_SLICE + tid;
            float hold = h_lds[j];
            float rg = sigmoidf_(gir + dots[tid]);
            float zg = sigmoidf_(giz + dots[16 + tid]);
            float ng = tanhf_(gin + rg * dots[32 + tid]);
            float hn = ng + zg * (hold - ng);
            unsigned long long pv =
                ((unsigned long long)(unsigned int)(t + 1) << 32) |
                (unsigned long long)__float_as_uint(hn);
            __hip_atomic_store(&hx[((t + 1) & 1) * H + j], pv,
                               __ATOMIC_RELAXED, __HIP_MEMORY_SCOPE_AGENT);
            out[(size_t)t * H + j] = hn;
            if (t == T - 1) out[(size_t)T * H + j] = hn;   // h_last tail
        }
        gir = ngir; giz = ngiz; gin = ngin;
        // no trailing barrier: next-iter h_lds overwrite is gated by the tag
        // poll, which transitively orders after this WG's reads of h_lds.
    }
}

// ---------------- launcher ----------------
extern "C" void kernel_launch(void* const* d_in, const int* in_sizes, int n_in,
                              void* d_out, int out_size, void* d_ws, size_t ws_size,
                              hipStream_t stream) {
    const float* x      = (const float*)d_in[0];
    const int*   ei     = (const int*)d_in[1];
    const float* hidden = (const float*)d_in[2];
    const float* gw     = (const float*)d_in[3];
    const float* gb     = (const float*)d_in[4];
    const float* w_ih   = (const float*)d_in[5];
    const float* w_hh   = (const float*)d_in[6];
    const float* b_ih   = (const float*)d_in[7];
    const float* b_hh   = (const float*)d_in[8];
    float* out = (float*)d_out;

    const int N = in_sizes[0] / D;   // 16384
    const int E = in_sizes[1] / 2;   // 262144

    // ws layout (floats): deg[16k] dinv[16k] hx[2048] elect | gcn[N*D] | gi[N*3H]
    float* ws   = (float*)d_ws;
    float* deg  = ws;
    float* dinv = ws + 16384;
    unsigned long long* hx = (unsigned long long*)(ws + 32768);
    int*   elect = (int*)(ws + 34816);
    float* gcn  = ws + 65536;
    float* gi   = gcn + (size_t)N * D;
    float* xw   = gi;   // alias: xw dies before gi is written

    deg_init<<<(N + 255) / 256, 256, 0, stream>>>(deg, N);
    deg_count<<<(E + 255) / 256, 256, 0, stream>>>(ei, deg, E);
    deg_inv<<<(N + 255) / 256, 256, 0, stream>>>(deg, dinv, N);

    gemm64<false, false><<<dim3(H / 64, N / 64), 256, 0, stream>>>(
        x, gw, nullptr, xw, N, H, D);

    gcn_init<<<N, 512, 0, stream>>>(xw, dinv, gb, gcn, N);
    scatter_edges<<<E, 512, 0, stream>>>(ei, xw, dinv, gcn, E);

    gemm64<true, true><<<dim3(G3 / 64, N / 64), 256, 0, stream>>>(
        gcn, w_ih, b_ih, gi, N, G3, H);

    gru_init<<<1, 512, 0, stream>>>(hidden, hx, elect);
    gru_kernel<<<256, GRU_THREADS, 0, stream>>>(
        gi, w_hh, b_hh, hx, elect, out, N);
}